// Round 3
// baseline (760.770 us; speedup 1.0000x reference)
//
#include <hip/hip_runtime.h>

#define HID 32
#define NODE_DIM 8

// 8-term dot of x-register pair against an 8-float weight row.
// NOTE: param must NOT be named 'w' / 'x' / 'y' / 'z' — macro substitution
// hits member accesses like (xb).w (R2 compile failure).
#define DOT8(xa, xb, WT) ((xa).x*(WT)[0] + (xa).y*(WT)[1] + (xa).z*(WT)[2] + (xa).w*(WT)[3] + \
                          (xb).x*(WT)[4] + (xb).y*(WT)[5] + (xb).z*(WT)[6] + (xb).w*(WT)[7])

// ---------------------------------------------------------------------------
// Edge kernel: one edge per wave (64 lanes), weight-stationary.
//   lane = (g, o): o = lane&31 output index, g = lane>>5 selects k-half.
//   W2 slice [g*16+kp][i][o] register-cached (128 VGPR/lane; whole wave holds
//   W2 exactly once). amdgpu_waves_per_eu(2,2) pins the allocator at the
//   256-VGPR budget so the cache stays in VGPRs (R1: compiler gave 104 VGPRs
//   and shuttled/reloaded -> 2x VALU insts).
//   1-deep software pipeline: next edge's idx/ea/x prefetched during compute.
// ---------------------------------------------------------------------------
__global__ __launch_bounds__(256)
__attribute__((amdgpu_waves_per_eu(2, 2)))
void edge_kernel(const float* __restrict__ x,
                 const float* __restrict__ ea,
                 const int* __restrict__ eidx,
                 const float* __restrict__ W1, const float* __restrict__ b1,
                 const float* __restrict__ W2, const float* __restrict__ b2,
                 float* __restrict__ s, int* __restrict__ cnt,
                 int E)
{
    const int tid  = blockIdx.x * blockDim.x + threadIdx.x;
    const int lane = threadIdx.x & 63;
    const int o    = lane & 31;
    const int g    = lane >> 5;
    const int wave = tid >> 6;
    const int nwav = (gridDim.x * blockDim.x) >> 6;

    // Register-cache W2 slice for this lane's (g, o).
    float w2r[16][8];
#pragma unroll
    for (int kp = 0; kp < 16; ++kp) {
        const float* wrow = W2 + (size_t)(g * 16 + kp) * (NODE_DIM * HID) + o;
#pragma unroll
        for (int i = 0; i < 8; ++i) w2r[kp][i] = wrow[i * 32];
    }
    float b2r[8];
#pragma unroll
    for (int i = 0; i < 8; ++i) b2r[i] = b2[i * 32 + o];

    // W1 column for k = o (h computed redundantly in both halves).
    const float w10 = W1[o], w11 = W1[32 + o], w12 = W1[64 + o], b1r = b1[o];

    int e = wave;
    if (e >= E) return;

    // ---- pipeline prologue: load edge e fully ----
    int    src_c = eidx[e];
    int    dst_c = eidx[E + e];
    float  ea0_c = ea[3 * e], ea1_c = ea[3 * e + 1], ea2_c = ea[3 * e + 2];
    float4 xa_c  = *(const float4*)(x + (size_t)src_c * 8);
    float4 xb_c  = *(const float4*)(x + (size_t)src_c * 8 + 4);

#pragma unroll 2
    for (; e < E; e += nwav) {
        // ---- prefetch next edge (clamped; redundant load on last iter) ----
        const int en = e + nwav;
        const int ep = en < E ? en : e;
        const int    src_n = eidx[ep];
        const int    dst_n = eidx[E + ep];
        const float  ea0_n = ea[3 * ep], ea1_n = ea[3 * ep + 1], ea2_n = ea[3 * ep + 2];
        const float4 xa_n  = *(const float4*)(x + (size_t)src_n * 8);
        const float4 xb_n  = *(const float4*)(x + (size_t)src_n * 8 + 4);

        // ---- compute current edge ----
        const float z = b1r + ea0_c * w10 + ea1_c * w11 + ea2_c * w12;
        const float h = z > 0.f ? z : 0.f;

        // b2 contribution counted once (g==0 half only)
        float acc = (g == 0) ? DOT8(xa_c, xb_c, b2r) : 0.f;

#pragma unroll
        for (int kp = 0; kp < 16; ++kp) {
            const float hk = __shfl(h, (g << 4) + kp, 32);   // h[g*16+kp]
            const float t  = DOT8(xa_c, xb_c, w2r[kp]);
            acc += hk * t;
        }

        acc += __shfl_xor(acc, 32, 64);   // combine the two k-halves

        if (g == 0)    atomicAdd(&s[(size_t)dst_c * 32 + o], acc);
        if (lane == 0) atomicAdd(&cnt[dst_c], 1);

        // ---- rotate pipeline regs ----
        dst_c = dst_n;
        ea0_c = ea0_n; ea1_c = ea1_n; ea2_c = ea2_n;
        xa_c  = xa_n;  xb_c  = xb_n;
    }
}

// ---------------------------------------------------------------------------
// Fused node-transform + per-graph pooling + MLP head. One 128-thread block
// per graph; batch is sorted so segment bounds come from binary search.
// Node transform (cnt-divide, root matmul, bias, relu) applied inline since
// each s element is consumed exactly once here.
// ---------------------------------------------------------------------------
__global__ __launch_bounds__(128)
void pool_mlp_kernel(const float* __restrict__ s,
                     const int* __restrict__ cnt,
                     const float* __restrict__ x,
                     const float* __restrict__ root,
                     const float* __restrict__ conv_bias,
                     const int* __restrict__ batch,
                     const float* __restrict__ ratios,
                     const int* __restrict__ ids,
                     const float* __restrict__ emb,
                     const float* __restrict__ fc0w, const float* __restrict__ fc0b,
                     const float* __restrict__ fc1w, const float* __restrict__ fc1b,
                     const float* __restrict__ fc2w, const float* __restrict__ fc2b,
                     float* __restrict__ out, int N)
{
    __shared__ float zs[96];
    __shared__ float z1[64];
    __shared__ float red[128];
    __shared__ int seg[2];

    const int g = blockIdx.x;
    const int t = threadIdx.x;

    if (t < 2) {
        const int target = g + t;
        int lo = 0, hi = N;
        while (lo < hi) {
            const int mid = (lo + hi) >> 1;
            if (batch[mid] < target) lo = mid + 1; else hi = mid;
        }
        seg[t] = lo;
    }
    __syncthreads();
    const int start = seg[0], end = seg[1];

    const int o = t & 31, chunk = t >> 5;

    // per-lane root column + bias
    float rootr[8];
#pragma unroll
    for (int i = 0; i < 8; ++i) rootr[i] = root[i * 32 + o];
    const float cb = conv_bias[o];

    float sum = 0.f;
    for (int n = start + chunk; n < end; n += 4) {
        const int   c    = cnt[n];
        const float rinv = 1.f / (float)(c > 1 ? c : 1);
        const float4 xa  = *(const float4*)(x + (size_t)n * 8);
        const float4 xb  = *(const float4*)(x + (size_t)n * 8 + 4);
        float v = s[(size_t)n * 32 + o] * rinv + cb + DOT8(xa, xb, rootr);
        sum += v > 0.f ? v : 0.f;
    }
    red[t] = sum;
    __syncthreads();

    if (t < 32) {
        const float p = red[t] + red[t + 32] + red[t + 64] + red[t + 96];
        float c = (float)(end - start);
        if (c < 1.f) c = 1.f;
        zs[t] = p / c;
    }
    if (t >= 32 && t < 96) {
        const int j = t - 32;  // u index 0..63
        float u = 0.f;
#pragma unroll
        for (int r = 0; r < 5; ++r) u += ratios[r] * emb[(size_t)ids[r] * 64 + j];
        zs[32 + j] = u;
    }
    __syncthreads();

    if (t < 64) {
        float a = fc0b[t];
        for (int k = 0; k < 96; ++k) a += zs[k] * fc0w[k * 64 + t];
        z1[t] = a > 0.f ? a : 0.f;
    }
    __syncthreads();

    if (t < 32) {
        float a = fc1b[t];
        for (int k = 0; k < 64; ++k) a += z1[k] * fc1w[k * 32 + t];
        red[t] = a > 0.f ? a : 0.f;  // reuse red[] as z2
    }
    __syncthreads();

    if (t == 0) {
        float a = fc2b[0];
        for (int k = 0; k < 32; ++k) a += red[k] * fc2w[k];
        out[g] = a;
    }
}

// ---------------------------------------------------------------------------
extern "C" void kernel_launch(void* const* d_in, const int* in_sizes, int n_in,
                              void* d_out, int out_size, void* d_ws, size_t ws_size,
                              hipStream_t stream)
{
    const float* x         = (const float*)d_in[0];
    const float* ea        = (const float*)d_in[1];
    const float* ratios    = (const float*)d_in[2];
    const int*   eidx      = (const int*)  d_in[3];
    const int*   batch     = (const int*)  d_in[4];
    const int*   ids       = (const int*)  d_in[5];
    const float* W1        = (const float*)d_in[6];
    const float* b1        = (const float*)d_in[7];
    const float* W2        = (const float*)d_in[8];
    const float* b2        = (const float*)d_in[9];
    const float* emb       = (const float*)d_in[10];
    const float* root      = (const float*)d_in[11];
    const float* conv_bias = (const float*)d_in[12];
    const float* fc0w      = (const float*)d_in[13];
    const float* fc0b      = (const float*)d_in[14];
    const float* fc1w      = (const float*)d_in[15];
    const float* fc1b      = (const float*)d_in[16];
    const float* fc2w      = (const float*)d_in[17];
    const float* fc2b      = (const float*)d_in[18];

    const int N = in_sizes[0] / NODE_DIM;   // 50000
    const int E = in_sizes[1] / 3;          // 1000000
    const int G = out_size;                 // 128

    float* s   = (float*)d_ws;                                   // [N,32]
    int*   cnt = (int*)((char*)d_ws + (size_t)N * 32 * 4);       // [N]
    (void)hipMemsetAsync(d_ws, 0, (size_t)N * 32 * 4 + (size_t)N * 4, stream);

    edge_kernel<<<1024, 256, 0, stream>>>(x, ea, eidx, W1, b1, W2, b2, s, cnt, E);
    pool_mlp_kernel<<<G, 128, 0, stream>>>(s, cnt, x, root, conv_bias, batch,
                                           ratios, ids, emb,
                                           fc0w, fc0b, fc1w, fc1b, fc2w, fc2b,
                                           (float*)d_out, N);
}

// Round 4
// 758.187 us; speedup vs baseline: 1.0034x; 1.0034x over previous
//
#include <hip/hip_runtime.h>

#define HID 32
#define NODE_DIM 8

// 8-term dot; param must not be named w/x/y/z (macro hits member access).
#define DOT8(xv, WT) ((xv)[0]*(WT)[0] + (xv)[1]*(WT)[1] + (xv)[2]*(WT)[2] + (xv)[3]*(WT)[3] + \
                      (xv)[4]*(WT)[4] + (xv)[5]*(WT)[5] + (xv)[6]*(WT)[6] + (xv)[7]*(WT)[7])

// ---------------------------------------------------------------------------
// Edge kernel: one edge per wave (64 lanes), weight-stationary.
//   lane = (g, o): o = lane&31 output index, g = lane>>5 selects k-half.
//   W2 slice [g*16+kp][i][o] lives in 128 VGPRs/lane; asm "+v" pins force
//   residency (R3: without pin, compiler rematerialized 128 L1 loads/edge ->
//   L1-BW-bound at 49% VALUBusy).
//   Loop index made uniform via readfirstlane so eidx/ea/x[src] compile to
//   s_loads (scalar pipe) and xv feeds v_fma as the SGPR operand.
// ---------------------------------------------------------------------------
__global__ __launch_bounds__(256)
__attribute__((amdgpu_waves_per_eu(2, 2)))
void edge_kernel(const float* __restrict__ x,
                 const float* __restrict__ ea,
                 const int* __restrict__ eidx,
                 const float* __restrict__ W1, const float* __restrict__ b1,
                 const float* __restrict__ W2, const float* __restrict__ b2,
                 float* __restrict__ s, int* __restrict__ cnt,
                 int E)
{
    const int lane = threadIdx.x & 63;
    const int o    = lane & 31;
    const int g    = lane >> 5;
    const int wave = (int)((blockIdx.x * blockDim.x + threadIdx.x) >> 6);
    const int nwav = (int)((gridDim.x * blockDim.x) >> 6);

    // Register-cache W2 slice for this lane's (g, o).
    float w2r[16][8];
#pragma unroll
    for (int kp = 0; kp < 16; ++kp) {
        const float* wrow = W2 + (size_t)(g * 16 + kp) * (NODE_DIM * HID) + o;
#pragma unroll
        for (int i = 0; i < 8; ++i) w2r[kp][i] = wrow[i * 32];
    }
    float b2r[8];
#pragma unroll
    for (int i = 0; i < 8; ++i) b2r[i] = b2[i * 32 + o];

    // Pin the weight cache into VGPRs: empty asm may "modify" the value, so
    // the compiler cannot rematerialize the load -> values stay live.
#pragma unroll
    for (int kp = 0; kp < 16; ++kp)
#pragma unroll
        for (int i = 0; i < 8; ++i)
            asm volatile("" : "+v"(w2r[kp][i]));
#pragma unroll
    for (int i = 0; i < 8; ++i)
        asm volatile("" : "+v"(b2r[i]));

    // W1 column for k = o (h computed redundantly in both halves).
    const float w10 = W1[o], w11 = W1[32 + o], w12 = W1[64 + o], b1r = b1[o];

    // Uniform loop chain: everything derived from wave_u is SGPR-resident,
    // so per-edge eidx/ea/x loads become s_load (scalar pipe, ~free).
    const int wave_u = __builtin_amdgcn_readfirstlane(wave);

    for (int e = wave_u; e < E; e += nwav) {
        const int src = eidx[e];
        const int dst = eidx[E + e];
        const float ea0 = ea[3 * e], ea1 = ea[3 * e + 1], ea2 = ea[3 * e + 2];

        const float* xp = x + (size_t)(unsigned)src * 8;
        float xv[8];
#pragma unroll
        for (int i = 0; i < 8; ++i) xv[i] = xp[i];   // uniform -> s_load

        const float z = b1r + ea0 * w10 + ea1 * w11 + ea2 * w12;
        const float h = z > 0.f ? z : 0.f;

        // b2 contribution counted once (g==0 half only)
        float acc = (g == 0) ? DOT8(xv, b2r) : 0.f;

#pragma unroll
        for (int kp = 0; kp < 16; ++kp) {
            const float hk = __shfl(h, (g << 4) + kp, 32);   // h[g*16+kp]
            const float t  = DOT8(xv, w2r[kp]);
            acc += hk * t;
        }

        acc += __shfl_xor(acc, 32, 64);   // combine the two k-halves

        if (g == 0)    atomicAdd(&s[(size_t)dst * 32 + o], acc);
        if (lane == 0) atomicAdd(&cnt[dst], 1);
    }
}

// ---------------------------------------------------------------------------
// Fused node-transform + per-graph pooling + MLP head. One 512-thread block
// per graph (16 node-chunks x 32 dims); batch sorted -> binary search.
// ---------------------------------------------------------------------------
__global__ __launch_bounds__(512)
void pool_mlp_kernel(const float* __restrict__ s,
                     const int* __restrict__ cnt,
                     const float* __restrict__ x,
                     const float* __restrict__ root,
                     const float* __restrict__ conv_bias,
                     const int* __restrict__ batch,
                     const float* __restrict__ ratios,
                     const int* __restrict__ ids,
                     const float* __restrict__ emb,
                     const float* __restrict__ fc0w, const float* __restrict__ fc0b,
                     const float* __restrict__ fc1w, const float* __restrict__ fc1b,
                     const float* __restrict__ fc2w, const float* __restrict__ fc2b,
                     float* __restrict__ out, int N)
{
    __shared__ float zs[96];
    __shared__ float z1[64];
    __shared__ float red[512];
    __shared__ int seg[2];

    const int g = blockIdx.x;
    const int t = threadIdx.x;

    if (t < 2) {
        const int target = g + t;
        int lo = 0, hi = N;
        while (lo < hi) {
            const int mid = (lo + hi) >> 1;
            if (batch[mid] < target) lo = mid + 1; else hi = mid;
        }
        seg[t] = lo;
    }
    __syncthreads();
    const int start = seg[0], end = seg[1];

    const int o = t & 31, chunk = t >> 5;   // chunk 0..15

    float rootr[8];
#pragma unroll
    for (int i = 0; i < 8; ++i) rootr[i] = root[i * 32 + o];
    const float cb = conv_bias[o];

    float sum = 0.f;
    for (int n = start + chunk; n < end; n += 16) {
        const int   c    = cnt[n];
        const float rinv = 1.f / (float)(c > 1 ? c : 1);
        const float* xp  = x + (size_t)n * 8;
        float xv[8];
#pragma unroll
        for (int i = 0; i < 8; ++i) xv[i] = xp[i];
        float v = s[(size_t)n * 32 + o] * rinv + cb + DOT8(xv, rootr);
        sum += v > 0.f ? v : 0.f;
    }
    red[t] = sum;
    __syncthreads();

    if (t < 32) {
        float p = 0.f;
#pragma unroll
        for (int c2 = 0; c2 < 16; ++c2) p += red[t + 32 * c2];
        float c = (float)(end - start);
        if (c < 1.f) c = 1.f;
        zs[t] = p / c;
    }
    if (t >= 32 && t < 96) {
        const int j = t - 32;  // u index 0..63
        float u = 0.f;
#pragma unroll
        for (int r = 0; r < 5; ++r) u += ratios[r] * emb[(size_t)ids[r] * 64 + j];
        zs[32 + j] = u;
    }
    __syncthreads();

    if (t < 64) {
        float a = fc0b[t];
        for (int k = 0; k < 96; ++k) a += zs[k] * fc0w[k * 64 + t];
        z1[t] = a > 0.f ? a : 0.f;
    }
    __syncthreads();

    if (t < 32) {
        float a = fc1b[t];
        for (int k = 0; k < 64; ++k) a += z1[k] * fc1w[k * 32 + t];
        red[t] = a > 0.f ? a : 0.f;  // reuse red[] as z2
    }
    __syncthreads();

    if (t == 0) {
        float a = fc2b[0];
        for (int k = 0; k < 32; ++k) a += red[k] * fc2w[k];
        out[g] = a;
    }
}

// ---------------------------------------------------------------------------
extern "C" void kernel_launch(void* const* d_in, const int* in_sizes, int n_in,
                              void* d_out, int out_size, void* d_ws, size_t ws_size,
                              hipStream_t stream)
{
    const float* x         = (const float*)d_in[0];
    const float* ea        = (const float*)d_in[1];
    const float* ratios    = (const float*)d_in[2];
    const int*   eidx      = (const int*)  d_in[3];
    const int*   batch     = (const int*)  d_in[4];
    const int*   ids       = (const int*)  d_in[5];
    const float* W1        = (const float*)d_in[6];
    const float* b1        = (const float*)d_in[7];
    const float* W2        = (const float*)d_in[8];
    const float* b2        = (const float*)d_in[9];
    const float* emb       = (const float*)d_in[10];
    const float* root      = (const float*)d_in[11];
    const float* conv_bias = (const float*)d_in[12];
    const float* fc0w      = (const float*)d_in[13];
    const float* fc0b      = (const float*)d_in[14];
    const float* fc1w      = (const float*)d_in[15];
    const float* fc1b      = (const float*)d_in[16];
    const float* fc2w      = (const float*)d_in[17];
    const float* fc2b      = (const float*)d_in[18];

    const int N = in_sizes[0] / NODE_DIM;   // 50000
    const int E = in_sizes[1] / 3;          // 1000000
    const int G = out_size;                 // 128

    float* s   = (float*)d_ws;                                   // [N,32]
    int*   cnt = (int*)((char*)d_ws + (size_t)N * 32 * 4);       // [N]
    (void)hipMemsetAsync(d_ws, 0, (size_t)N * 32 * 4 + (size_t)N * 4, stream);

    edge_kernel<<<1024, 256, 0, stream>>>(x, ea, eidx, W1, b1, W2, b2, s, cnt, E);
    pool_mlp_kernel<<<G, 512, 0, stream>>>(s, cnt, x, root, conv_bias, batch,
                                           ratios, ids, emb,
                                           fc0w, fc0b, fc1w, fc1b, fc2w, fc2b,
                                           (float*)d_out, N);
}

// Round 5
// 586.609 us; speedup vs baseline: 1.2969x; 1.2925x over previous
//
#include <hip/hip_runtime.h>

#define HID 32
#define NODE_DIM 8

// 8-term dot; param must not be named w/x/y/z (macro hits member access).
#define DOT8(xv, WT) ((xv)[0]*(WT)[0] + (xv)[1]*(WT)[1] + (xv)[2]*(WT)[2] + (xv)[3]*(WT)[3] + \
                      (xv)[4]*(WT)[4] + (xv)[5]*(WT)[5] + (xv)[6]*(WT)[6] + (xv)[7]*(WT)7[7-7])
#undef DOT8
#define DOT8(xv, WT) ((xv)[0]*(WT)[0] + (xv)[1]*(WT)[1] + (xv)[2]*(WT)[2] + (xv)[3]*(WT)[3] + \
                      (xv)[4]*(WT)[4] + (xv)[5]*(WT)[5] + (xv)[6]*(WT)[6] + (xv)[7]*(WT)[7])

// ---------------------------------------------------------------------------
// Edge kernel R5: TWO waves per edge (k split 16/16) so the weight cache is
// only w2r[8][8] = 64 VGPR/lane (R1-R4: 128-float cache always got demoted to
// AGPR/scratch shuttling -> 2x VALU insts at <50% busy). ~95 VGPR total fits
// the 128 budget of __launch_bounds__(256,4) with slack -> no remat pressure.
//
// Block = 4 waves, tile = 4 edges/iteration:
//   wave w: q = w&1 (k-half), jb = w>>1; handles edges base+jb, base+jb+2.
//   lane = (g,o): o = lane&31 output, g = lane>>5 -> k = q*16 + g*8 + kp.
// Partials (g-combined via shfl_xor) land in LDS part[q][j][o]; a combine
// phase after __syncthreads issues ONE atomic per (edge,o) -> atomic count
// unchanged vs R4 (33M).
// ---------------------------------------------------------------------------
__global__ __launch_bounds__(256, 4)
void edge_kernel(const float* __restrict__ x,
                 const float* __restrict__ ea,
                 const int* __restrict__ eidx,
                 const float* __restrict__ W1, const float* __restrict__ b1,
                 const float* __restrict__ W2, const float* __restrict__ b2,
                 float* __restrict__ s, int* __restrict__ cnt,
                 int E)
{
    __shared__ float part[2][4][32];

    const int tid  = threadIdx.x;
    const int lane = tid & 63;
    const int o    = lane & 31;
    const int g    = lane >> 5;
    const int w    = __builtin_amdgcn_readfirstlane(tid >> 6);  // 0..3, uniform
    const int q    = w & 1;    // k-half of the edge
    const int jb   = w >> 1;   // edge sub-slot: handles jb and jb+2

    // Weight cache: k = q*16 + g*8 + kp, 64 floats/lane.
    float w2r[8][8];
#pragma unroll
    for (int kp = 0; kp < 8; ++kp) {
        const float* wrow = W2 + (size_t)(q * 16 + g * 8 + kp) * (NODE_DIM * HID) + o;
#pragma unroll
        for (int i = 0; i < 8; ++i) w2r[kp][i] = wrow[i * 32];
    }
    float b2r[8];
#pragma unroll
    for (int i = 0; i < 8; ++i) b2r[i] = b2[i * 32 + o];

    // h-lane mapping: lane computes h[e, kh], kh = q*16 + (lane&15).
    const int kh = q * 16 + (lane & 15);
    const float w10 = W1[kh], w11 = W1[32 + kh], w12 = W1[64 + kh], b1r = b1[kh];

    const int Em1 = E - 1;

    for (int base = blockIdx.x * 4; base < E; base += gridDim.x * 4) {
        const int e0 = base + jb     <= Em1 ? base + jb     : Em1;
        const int e1 = base + jb + 2 <= Em1 ? base + jb + 2 : Em1;

        // Uniform scalar loads (edge metadata + source node feats -> SGPRs).
        const float ea00 = ea[3 * e0], ea01 = ea[3 * e0 + 1], ea02 = ea[3 * e0 + 2];
        const float ea10 = ea[3 * e1], ea11 = ea[3 * e1 + 1], ea12 = ea[3 * e1 + 2];
        const int src0 = eidx[e0], src1 = eidx[e1];
        const float* xp0 = x + (size_t)(unsigned)src0 * 8;
        const float* xp1 = x + (size_t)(unsigned)src1 * 8;
        float xv0[8], xv1[8];
#pragma unroll
        for (int i = 0; i < 8; ++i) { xv0[i] = xp0[i]; xv1[i] = xp1[i]; }

        const float z0 = b1r + ea00 * w10 + ea01 * w11 + ea02 * w12;
        const float z1 = b1r + ea10 * w10 + ea11 * w11 + ea12 * w12;
        const float h0 = z0 > 0.f ? z0 : 0.f;
        const float h1 = z1 > 0.f ? z1 : 0.f;

        // b2 contribution counted once per edge: q==0 wave, g==0 half.
        const bool take_b2 = (q == 0) && (g == 0);
        float acc0 = take_b2 ? DOT8(xv0, b2r) : 0.f;
        float acc1 = take_b2 ? DOT8(xv1, b2r) : 0.f;

#pragma unroll
        for (int kp = 0; kp < 8; ++kp) {
            const float hk0 = __shfl(h0, g * 8 + kp, 16);   // h[q*16 + g*8 + kp]
            const float hk1 = __shfl(h1, g * 8 + kp, 16);
            acc0 += hk0 * DOT8(xv0, w2r[kp]);
            acc1 += hk1 * DOT8(xv1, w2r[kp]);
        }

        acc0 += __shfl_xor(acc0, 32);   // fold g=1 half into g=0
        acc1 += __shfl_xor(acc1, 32);

        if (g == 0) {
            part[q][jb][o]     = acc0;
            part[q][jb + 2][o] = acc1;
        }
        __syncthreads();

        // Combine phase: 128 threads = 4 edges x 32 outputs, one atomic each.
        if (tid < 128) {
            const int j  = tid >> 5, oo = tid & 31;
            const int ej = base + j;
            if (ej < E) {
                const float v = part[0][j][oo] + part[1][j][oo];
                const int dst = eidx[E + ej];
                atomicAdd(&s[(size_t)(unsigned)dst * 32 + oo], v);
                if (oo == 0) atomicAdd(&cnt[dst], 1);
            }
        }
        __syncthreads();
    }
}

// ---------------------------------------------------------------------------
// Fused node-transform + per-graph pooling + MLP head. One 512-thread block
// per graph (16 node-chunks x 32 dims); batch sorted -> binary search.
// ---------------------------------------------------------------------------
__global__ __launch_bounds__(512)
void pool_mlp_kernel(const float* __restrict__ s,
                     const int* __restrict__ cnt,
                     const float* __restrict__ x,
                     const float* __restrict__ root,
                     const float* __restrict__ conv_bias,
                     const int* __restrict__ batch,
                     const float* __restrict__ ratios,
                     const int* __restrict__ ids,
                     const float* __restrict__ emb,
                     const float* __restrict__ fc0w, const float* __restrict__ fc0b,
                     const float* __restrict__ fc1w, const float* __restrict__ fc1b,
                     const float* __restrict__ fc2w, const float* __restrict__ fc2b,
                     float* __restrict__ out, int N)
{
    __shared__ float zs[96];
    __shared__ float z1[64];
    __shared__ float red[512];
    __shared__ int seg[2];

    const int g = blockIdx.x;
    const int t = threadIdx.x;

    if (t < 2) {
        const int target = g + t;
        int lo = 0, hi = N;
        while (lo < hi) {
            const int mid = (lo + hi) >> 1;
            if (batch[mid] < target) lo = mid + 1; else hi = mid;
        }
        seg[t] = lo;
    }
    __syncthreads();
    const int start = seg[0], end = seg[1];

    const int o = t & 31, chunk = t >> 5;   // chunk 0..15

    float rootr[8];
#pragma unroll
    for (int i = 0; i < 8; ++i) rootr[i] = root[i * 32 + o];
    const float cb = conv_bias[o];

    float sum = 0.f;
    for (int n = start + chunk; n < end; n += 16) {
        const int   c    = cnt[n];
        const float rinv = 1.f / (float)(c > 1 ? c : 1);
        const float* xp  = x + (size_t)n * 8;
        float xv[8];
#pragma unroll
        for (int i = 0; i < 8; ++i) xv[i] = xp[i];
        float v = s[(size_t)n * 32 + o] * rinv + cb + DOT8(xv, rootr);
        sum += v > 0.f ? v : 0.f;
    }
    red[t] = sum;
    __syncthreads();

    if (t < 32) {
        float p = 0.f;
#pragma unroll
        for (int c2 = 0; c2 < 16; ++c2) p += red[t + 32 * c2];
        float c = (float)(end - start);
        if (c < 1.f) c = 1.f;
        zs[t] = p / c;
    }
    if (t >= 32 && t < 96) {
        const int j = t - 32;  // u index 0..63
        float u = 0.f;
#pragma unroll
        for (int r = 0; r < 5; ++r) u += ratios[r] * emb[(size_t)ids[r] * 64 + j];
        zs[32 + j] = u;
    }
    __syncthreads();

    if (t < 64) {
        float a = fc0b[t];
        for (int k = 0; k < 96; ++k) a += zs[k] * fc0w[k * 64 + t];
        z1[t] = a > 0.f ? a : 0.f;
    }
    __syncthreads();

    if (t < 32) {
        float a = fc1b[t];
        for (int k = 0; k < 64; ++k) a += z1[k] * fc1w[k * 32 + t];
        red[t] = a > 0.f ? a : 0.f;  // reuse red[] as z2
    }
    __syncthreads();

    if (t == 0) {
        float a = fc2b[0];
        for (int k = 0; k < 32; ++k) a += red[k] * fc2w[k];
        out[g] = a;
    }
}

// ---------------------------------------------------------------------------
extern "C" void kernel_launch(void* const* d_in, const int* in_sizes, int n_in,
                              void* d_out, int out_size, void* d_ws, size_t ws_size,
                              hipStream_t stream)
{
    const float* x         = (const float*)d_in[0];
    const float* ea        = (const float*)d_in[1];
    const float* ratios    = (const float*)d_in[2];
    const int*   eidx      = (const int*)  d_in[3];
    const int*   batch     = (const int*)  d_in[4];
    const int*   ids       = (const int*)  d_in[5];
    const float* W1        = (const float*)d_in[6];
    const float* b1        = (const float*)d_in[7];
    const float* W2        = (const float*)d_in[8];
    const float* b2        = (const float*)d_in[9];
    const float* emb       = (const float*)d_in[10];
    const float* root      = (const float*)d_in[11];
    const float* conv_bias = (const float*)d_in[12];
    const float* fc0w      = (const float*)d_in[13];
    const float* fc0b      = (const float*)d_in[14];
    const float* fc1w      = (const float*)d_in[15];
    const float* fc1b      = (const float*)d_in[16];
    const float* fc2w      = (const float*)d_in[17];
    const float* fc2b      = (const float*)d_in[18];

    const int N = in_sizes[0] / NODE_DIM;   // 50000
    const int E = in_sizes[1] / 3;          // 1000000
    const int G = out_size;                 // 128

    float* s   = (float*)d_ws;                                   // [N,32]
    int*   cnt = (int*)((char*)d_ws + (size_t)N * 32 * 4);       // [N]
    (void)hipMemsetAsync(d_ws, 0, (size_t)N * 32 * 4 + (size_t)N * 4, stream);

    edge_kernel<<<1024, 256, 0, stream>>>(x, ea, eidx, W1, b1, W2, b2, s, cnt, E);
    pool_mlp_kernel<<<G, 512, 0, stream>>>(s, cnt, x, root, conv_bias, batch,
                                           ratios, ids, emb,
                                           fc0w, fc0b, fc1w, fc1b, fc2w, fc2b,
                                           (float*)d_out, N);
}

// Round 6
// 457.719 us; speedup vs baseline: 1.6621x; 1.2816x over previous
//
#include <hip/hip_runtime.h>

#define HID 32
#define NODE_DIM 8
#define EPG 8   // edges per group per wave

// 8-term dot; param must not be named w/x/y/z (macro hits member access).
#define DOT8(xv, WT) ((xv)[0]*(WT)[0] + (xv)[1]*(WT)[1] + (xv)[2]*(WT)[2] + (xv)[3]*(WT)[3] + \
                      (xv)[4]*(WT)[4] + (xv)[5]*(WT)[5] + (xv)[6]*(WT)[6] + (xv)[7]*(WT)[7])

// ---------------------------------------------------------------------------
// Edge kernel R6: stream W2, don't cache it (R1-R5: allocator never keeps a
// per-lane weight array resident). One wave per 8-edge group, full K=32:
//   lane=(g,o): o=lane&31 output, g=lane>>5; k = g*16+kp, kp=0..15.
//   Per kp: load W2 row pair (8 coalesced dwords, double-buffered -> live set
//   16 floats) and reuse it across all 8 edges -> 16 W2 loads/edge (was 32).
//   h[e,k]: lane holds k = g*16+(lane&15); __shfl(h, kp, 16) is wave-uniform
//   src -> static swizzle broadcast within each 16-group.
//   Edge metadata + x[src] forced scalar (readfirstlane) -> xv in SGPRs,
//   v_fma uses its one legal SGPR operand.
//   No LDS, no block barriers: g=0 half issues atomics directly.
// ---------------------------------------------------------------------------
__global__ __launch_bounds__(256)
void edge_kernel(const float* __restrict__ x,
                 const float* __restrict__ ea,
                 const int* __restrict__ eidx,
                 const float* __restrict__ W1, const float* __restrict__ b1,
                 const float* __restrict__ W2, const float* __restrict__ b2,
                 float* __restrict__ s, int* __restrict__ cnt,
                 int E)
{
    const int lane = threadIdx.x & 63;
    const int o    = lane & 31;
    const int g    = lane >> 5;
    const int wave = (int)((blockIdx.x * blockDim.x + threadIdx.x) >> 6);
    const int nwav = (int)((gridDim.x * blockDim.x) >> 6);
    const int wave_u = __builtin_amdgcn_readfirstlane(wave);

    float b2r[8];
#pragma unroll
    for (int i = 0; i < 8; ++i) b2r[i] = b2[i * 32 + o];

    // h-lane mapping: lane computes h[e, kh], kh = g*16 + (lane&15), so the
    // kp-broadcast is __shfl(h, kp, 16) with uniform src.
    const int kh = (g << 4) | (lane & 15);
    const float w10 = W1[kh], w11 = W1[32 + kh], w12 = W1[64 + kh], b1r = b1[kh];

    const int ngrp = (E + EPG - 1) / EPG;
    const int Em1  = E - 1;

    for (int grp = wave_u; grp < ngrp; grp += nwav) {
        const int base = grp * EPG;

        // ---- scalar phase: 8 edges' metadata + source rows into SGPRs ----
        float xv[EPG][8];
        float h[EPG];
        int   dst[EPG];
#pragma unroll
        for (int j = 0; j < EPG; ++j) {
            int ej = base + j; ej = ej <= Em1 ? ej : Em1;
            const int src = __builtin_amdgcn_readfirstlane(eidx[ej]);
            dst[j]        = __builtin_amdgcn_readfirstlane(eidx[E + ej]);
            const float e0 = ea[3 * ej], e1 = ea[3 * ej + 1], e2 = ea[3 * ej + 2];
            const float* xp = x + (size_t)(unsigned)src * 8;
#pragma unroll
            for (int i = 0; i < 8; ++i) xv[j][i] = xp[i];
            const float z = b1r + e0 * w10 + e1 * w11 + e2 * w12;
            h[j] = z > 0.f ? z : 0.f;
        }

        // b2 contribution counted once per edge (g==0 half).
        float acc[EPG];
#pragma unroll
        for (int j = 0; j < EPG; ++j) acc[j] = (g == 0) ? DOT8(xv[j], b2r) : 0.f;

        // ---- stream W2 rows: k = g*16 + kp, double-buffered ----
        const float* wbase = W2 + (size_t)(g * 16) * (NODE_DIM * HID) + o;
        float w2cur[8];
#pragma unroll
        for (int i = 0; i < 8; ++i) w2cur[i] = wbase[i * 32];

#pragma unroll 2
        for (int kp = 0; kp < 16; ++kp) {
            float w2nxt[8];
            const int kn = kp + 1 <= 15 ? kp + 1 : 15;
            const float* wn = wbase + (size_t)kn * (NODE_DIM * HID);
#pragma unroll
            for (int i = 0; i < 8; ++i) w2nxt[i] = wn[i * 32];

#pragma unroll
            for (int j = 0; j < EPG; ++j) {
                const float hk = __shfl(h[j], kp, 16);   // h[ej, g*16+kp]
                acc[j] += hk * DOT8(xv[j], w2cur);
            }
#pragma unroll
            for (int i = 0; i < 8; ++i) w2cur[i] = w2nxt[i];
        }

        // ---- fold halves, scatter ----
#pragma unroll
        for (int j = 0; j < EPG; ++j) {
            float a = acc[j];
            a += __shfl_xor(a, 32);
            const int ej = base + j;
            if (g == 0 && ej < E) {
                atomicAdd(&s[(size_t)(unsigned)dst[j] * 32 + o], a);
                if (o == 0) atomicAdd(&cnt[dst[j]], 1);
            }
        }
    }
}

// ---------------------------------------------------------------------------
// Node transform + partial pool: grid-stride, 256 threads = 8 nodes x 32 dims.
// v = relu(s/cnt + x@root + cb); blocks whose 8 nodes share one graph (the
// common case, segments ~390 nodes) LDS-reduce to ONE atomic per (block,o);
// boundary blocks fall back to per-thread atomics.
// ---------------------------------------------------------------------------
__global__ __launch_bounds__(256)
void node_pool_kernel(const float* __restrict__ s,
                      const int* __restrict__ cnt,
                      const float* __restrict__ x,
                      const float* __restrict__ root,
                      const float* __restrict__ conv_bias,
                      const int* __restrict__ batch,
                      float* __restrict__ gsum, int N)
{
    __shared__ float red[256];
    const int t    = threadIdx.x;
    const int o    = t & 31;
    const int slot = t >> 5;                 // 0..7
    const int base = blockIdx.x * 8;
    const int n    = base + slot;

    float rootr[8];
#pragma unroll
    for (int i = 0; i < 8; ++i) rootr[i] = root[i * 32 + o];
    const float cb = conv_bias[o];

    float v = 0.f;
    int   b = 0;
    if (n < N) {
        b = batch[n];
        const int   c    = cnt[n];
        const float rinv = 1.f / (float)(c > 1 ? c : 1);
        const float* xp  = x + (size_t)n * 8;
        float xv[8];
#pragma unroll
        for (int i = 0; i < 8; ++i) xv[i] = xp[i];
        const float t2 = s[(size_t)n * 32 + o] * rinv + cb + DOT8(xv, rootr);
        v = t2 > 0.f ? t2 : 0.f;
    }

    const int nlast  = (base + 7 < N) ? base + 7 : N - 1;
    const int bfirst = batch[base];
    const int blast  = batch[nlast];

    if (bfirst == blast && base + 7 < N) {
        red[t] = v;
        __syncthreads();
        if (t < 32) {
            float p = 0.f;
#pragma unroll
            for (int c2 = 0; c2 < 8; ++c2) p += red[t + 32 * c2];
            atomicAdd(&gsum[bfirst * 32 + t], p);
        }
    } else {
        if (n < N) atomicAdd(&gsum[b * 32 + o], v);
    }
}

// ---------------------------------------------------------------------------
// MLP head: one 128-thread block per graph; gc from binary search on batch.
// ---------------------------------------------------------------------------
__global__ __launch_bounds__(128)
void mlp_kernel(const float* __restrict__ gsum,
                const int* __restrict__ batch,
                const float* __restrict__ ratios,
                const int* __restrict__ ids,
                const float* __restrict__ emb,
                const float* __restrict__ fc0w, const float* __restrict__ fc0b,
                const float* __restrict__ fc1w, const float* __restrict__ fc1b,
                const float* __restrict__ fc2w, const float* __restrict__ fc2b,
                float* __restrict__ out, int N)
{
    __shared__ float zs[96];
    __shared__ float z1[64];
    __shared__ float z2[32];
    __shared__ int seg[2];

    const int g = blockIdx.x;
    const int t = threadIdx.x;

    if (t < 2) {
        const int target = g + t;
        int lo = 0, hi = N;
        while (lo < hi) {
            const int mid = (lo + hi) >> 1;
            if (batch[mid] < target) lo = mid + 1; else hi = mid;
        }
        seg[t] = lo;
    }
    __syncthreads();

    float c = (float)(seg[1] - seg[0]);
    if (c < 1.f) c = 1.f;

    if (t < 32) zs[t] = gsum[g * 32 + t] / c;
    if (t >= 32 && t < 96) {
        const int j = t - 32;
        float u = 0.f;
#pragma unroll
        for (int r = 0; r < 5; ++r) u += ratios[r] * emb[(size_t)ids[r] * 64 + j];
        zs[32 + j] = u;
    }
    __syncthreads();

    if (t < 64) {
        float a = fc0b[t];
        for (int k = 0; k < 96; ++k) a += zs[k] * fc0w[k * 64 + t];
        z1[t] = a > 0.f ? a : 0.f;
    }
    __syncthreads();

    if (t < 32) {
        float a = fc1b[t];
        for (int k = 0; k < 64; ++k) a += z1[k] * fc1w[k * 32 + t];
        z2[t] = a > 0.f ? a : 0.f;
    }
    __syncthreads();

    if (t == 0) {
        float a = fc2b[0];
        for (int k = 0; k < 32; ++k) a += z2[k] * fc2w[k];
        out[g] = a;
    }
}

// ---------------------------------------------------------------------------
extern "C" void kernel_launch(void* const* d_in, const int* in_sizes, int n_in,
                              void* d_out, int out_size, void* d_ws, size_t ws_size,
                              hipStream_t stream)
{
    const float* x         = (const float*)d_in[0];
    const float* ea        = (const float*)d_in[1];
    const float* ratios    = (const float*)d_in[2];
    const int*   eidx      = (const int*)  d_in[3];
    const int*   batch     = (const int*)  d_in[4];
    const int*   ids       = (const int*)  d_in[5];
    const float* W1        = (const float*)d_in[6];
    const float* b1        = (const float*)d_in[7];
    const float* W2        = (const float*)d_in[8];
    const float* b2        = (const float*)d_in[9];
    const float* emb       = (const float*)d_in[10];
    const float* root      = (const float*)d_in[11];
    const float* conv_bias = (const float*)d_in[12];
    const float* fc0w      = (const float*)d_in[13];
    const float* fc0b      = (const float*)d_in[14];
    const float* fc1w      = (const float*)d_in[15];
    const float* fc1b      = (const float*)d_in[16];
    const float* fc2w      = (const float*)d_in[17];
    const float* fc2b      = (const float*)d_in[18];

    const int N = in_sizes[0] / NODE_DIM;   // 50000
    const int E = in_sizes[1] / 3;          // 1000000
    const int G = out_size;                 // 128

    float* s    = (float*)d_ws;                                        // [N,32]
    int*   cnt  = (int*)((char*)d_ws + (size_t)N * 32 * 4);            // [N]
    float* gsum = (float*)((char*)d_ws + (size_t)N * 32 * 4 + (size_t)N * 4); // [G,32]
    (void)hipMemsetAsync(d_ws, 0, (size_t)N * 32 * 4 + (size_t)N * 4 + (size_t)G * 32 * 4, stream);

    edge_kernel<<<2048, 256, 0, stream>>>(x, ea, eidx, W1, b1, W2, b2, s, cnt, E);
    node_pool_kernel<<<(N + 7) / 8, 256, 0, stream>>>(s, cnt, x, root, conv_bias,
                                                      batch, gsum, N);
    mlp_kernel<<<G, 128, 0, stream>>>(gsum, batch, ratios, ids, emb,
                                      fc0w, fc0b, fc1w, fc1b, fc2w, fc2b,
                                      (float*)d_out, N);
}

// Round 7
// 280.452 us; speedup vs baseline: 2.7127x; 1.6321x over previous
//
#include <hip/hip_runtime.h>

#define NODE_DIM 8

typedef __attribute__((ext_vector_type(8))) short short8;
typedef __attribute__((ext_vector_type(4))) float f32x4;

// 8-term dot; param must not be named w/x/y/z (macro hits member access).
#define DOT8(xv, WT) ((xv)[0]*(WT)[0] + (xv)[1]*(WT)[1] + (xv)[2]*(WT)[2] + (xv)[3]*(WT)[3] + \
                      (xv)[4]*(WT)[4] + (xv)[5]*(WT)[5] + (xv)[6]*(WT)[6] + (xv)[7]*(WT)[7])

// RNE fp32->bf16, packed pair (a -> low16, b -> high16).
static __device__ __forceinline__ unsigned pk_bf16(float a, float b) {
    unsigned ua = __float_as_uint(a), ub = __float_as_uint(b);
    ua = (ua + 0x7fffu + ((ua >> 16) & 1u)) >> 16;
    ub = (ub + 0x7fffu + ((ub >> 16) & 1u)) & 0xffff0000u;
    return (ua & 0xffffu) | ub;
}

// ---------------------------------------------------------------------------
// Edge kernel R7: the per-edge matvec IS a GEMM — [E,256] @ [256,32] with
// f[e, c=(k<<3|i)] = h[e,k] * x[src[e], i].  MFMA 16x16x32_bf16, one wave per
// 16-edge group, K = 9 steps of 32 (step 8 = b2 bias row-extension, "h"=1).
//
//   A-layout (m120): A[m=lane&15][c = q*8+j], q=lane>>4.  With c=(k<<3|i):
//   k = 4*kk+q, i = j  ->  a_j = h[e, 4kk+q] * x[e, j].  Lane precomputes
//   h[e, 4t+q] (t=0..7) -> A-frag = 8 muls + 4 RNE packs, NO shuffle.
//   B = W2R (+b2 rows), constant: staged bf16 in LDS in exact B-frag order
//   (lane n=lane&15, c=q*8+j), 18 frags = 18 KB, 2 ds_read_b128/step.
//   C/D (m89): col=lane&15 = o_local, row=(lane>>4)*4+reg = edge slot.
//   Accumulate fp32; scatter-mean atomics unchanged (32/edge).
// ---------------------------------------------------------------------------
__global__ __launch_bounds__(256)
void edge_kernel(const float* __restrict__ x,
                 const float* __restrict__ ea,
                 const int* __restrict__ eidx,
                 const float* __restrict__ W1, const float* __restrict__ b1,
                 const float* __restrict__ W2, const float* __restrict__ b2,
                 float* __restrict__ s, int* __restrict__ cnt,
                 int E)
{
    __shared__ __align__(16) short lds_b[18 * 64 * 8];

    const int t = threadIdx.x;

    // ---- stage B fragments (bf16, frag-order) once per block ----
    for (int f = t; f < 18 * 64 * 8; f += 256) {
        const int j   = f & 7;
        const int ln  = (f >> 3) & 63;
        const int fid = f >> 9;            // 0..17
        const int kk  = fid >> 1, ot = fid & 1;
        const int qq  = ln >> 4, ol = ln & 15;
        float v;
        if (kk < 8) v = W2[(kk * 4 + qq) * 256 + j * 32 + ot * 16 + ol];
        else        v = (qq == 0) ? b2[j * 32 + ot * 16 + ol] : 0.f;
        unsigned uv = __float_as_uint(v);
        uv = (uv + 0x7fffu + ((uv >> 16) & 1u)) >> 16;
        lds_b[f] = (short)uv;
    }
    __syncthreads();

    const int lane = t & 63;
    const int e_l  = lane & 15;    // edge slot within group (A: m, C: n!)
    const int q    = lane >> 4;    // quad

    // W1 columns for this lane's h set: k = 4t+q.
    float w10[8], w11[8], w12[8], b1r[8];
#pragma unroll
    for (int t2 = 0; t2 < 8; ++t2) {
        const int k = 4 * t2 + q;
        w10[t2] = W1[k]; w11[t2] = W1[32 + k]; w12[t2] = W1[64 + k]; b1r[t2] = b1[k];
    }

    const int wave = blockIdx.x * 4 + (t >> 6);
    const int nwav = gridDim.x * 4;
    const int ngrp = (E + 15) / 16;

    for (int grp = wave; grp < ngrp; grp += nwav) {
        const int base = grp * 16;
        int ej = base + e_l; if (ej >= E) ej = E - 1;
        const int src = eidx[ej];
        const int dst = eidx[E + ej];
        const float ea0 = ea[3 * ej], ea1 = ea[3 * ej + 1], ea2 = ea[3 * ej + 2];
        const float4 xa = *(const float4*)(x + (size_t)(unsigned)src * 8);
        const float4 xb = *(const float4*)(x + (size_t)(unsigned)src * 8 + 4);
        const float xr[8] = {xa.x, xa.y, xa.z, xa.w, xb.x, xb.y, xb.z, xb.w};

        float h[8];
#pragma unroll
        for (int t2 = 0; t2 < 8; ++t2) {
            const float z = b1r[t2] + ea0 * w10[t2] + ea1 * w11[t2] + ea2 * w12[t2];
            h[t2] = z > 0.f ? z : 0.f;
        }

        f32x4 acc0 = {0.f, 0.f, 0.f, 0.f};
        f32x4 acc1 = {0.f, 0.f, 0.f, 0.f};

#pragma unroll
        for (int kk = 0; kk < 9; ++kk) {
            const float hk = (kk < 8) ? h[kk] : 1.f;   // step 8: bias rows (B has zeros for q>0)
            union { short8 v; unsigned u[4]; } af;
#pragma unroll
            for (int p = 0; p < 4; ++p)
                af.u[p] = pk_bf16(hk * xr[2 * p], hk * xr[2 * p + 1]);
            const short8 bf0 = *(const short8*)&lds_b[((kk * 2 + 0) * 64 + lane) * 8];
            const short8 bf1 = *(const short8*)&lds_b[((kk * 2 + 1) * 64 + lane) * 8];
            acc0 = __builtin_amdgcn_mfma_f32_16x16x32_bf16(af.v, bf0, acc0, 0, 0, 0);
            acc1 = __builtin_amdgcn_mfma_f32_16x16x32_bf16(af.v, bf1, acc1, 0, 0, 0);
        }

        // ---- scatter: C row m = q*4+r (edge base+m), col = e_l (o_local) ----
#pragma unroll
        for (int r = 0; r < 4; ++r) {
            const int m  = q * 4 + r;
            const int eg = base + m;
            const int dr = __shfl(dst, m, 16);   // dst held by lane with e_l==m
            if (eg < E) {
                atomicAdd(&s[(size_t)(unsigned)dr * 32 + e_l],      acc0[r]);
                atomicAdd(&s[(size_t)(unsigned)dr * 32 + 16 + e_l], acc1[r]);
            }
        }
        if (lane < 16 && base + e_l < E) atomicAdd(&cnt[dst], 1);
    }
}

// ---------------------------------------------------------------------------
// Node transform + partial pool: 256 threads = 8 nodes x 32 dims; blocks whose
// nodes share one graph LDS-reduce to one atomic per (block,o).
// ---------------------------------------------------------------------------
__global__ __launch_bounds__(256)
void node_pool_kernel(const float* __restrict__ s,
                      const int* __restrict__ cnt,
                      const float* __restrict__ x,
                      const float* __restrict__ root,
                      const float* __restrict__ conv_bias,
                      const int* __restrict__ batch,
                      float* __restrict__ gsum, int N)
{
    __shared__ float red[256];
    const int t    = threadIdx.x;
    const int o    = t & 31;
    const int slot = t >> 5;
    const int base = blockIdx.x * 8;
    const int n    = base + slot;

    float rootr[8];
#pragma unroll
    for (int i = 0; i < 8; ++i) rootr[i] = root[i * 32 + o];
    const float cb = conv_bias[o];

    float v = 0.f;
    int   b = 0;
    if (n < N) {
        b = batch[n];
        const int   c    = cnt[n];
        const float rinv = 1.f / (float)(c > 1 ? c : 1);
        const float* xp  = x + (size_t)n * 8;
        float xv[8];
#pragma unroll
        for (int i = 0; i < 8; ++i) xv[i] = xp[i];
        const float t2 = s[(size_t)n * 32 + o] * rinv + cb + DOT8(xv, rootr);
        v = t2 > 0.f ? t2 : 0.f;
    }

    const int nlast  = (base + 7 < N) ? base + 7 : N - 1;
    const int bfirst = batch[base];
    const int blast  = batch[nlast];

    if (bfirst == blast && base + 7 < N) {
        red[t] = v;
        __syncthreads();
        if (t < 32) {
            float p = 0.f;
#pragma unroll
            for (int c2 = 0; c2 < 8; ++c2) p += red[t + 32 * c2];
            atomicAdd(&gsum[bfirst * 32 + t], p);
        }
    } else {
        if (n < N) atomicAdd(&gsum[b * 32 + o], v);
    }
}

// ---------------------------------------------------------------------------
// MLP head: one 128-thread block per graph.
// ---------------------------------------------------------------------------
__global__ __launch_bounds__(128)
void mlp_kernel(const float* __restrict__ gsum,
                const int* __restrict__ batch,
                const float* __restrict__ ratios,
                const int* __restrict__ ids,
                const float* __restrict__ emb,
                const float* __restrict__ fc0w, const float* __restrict__ fc0b,
                const float* __restrict__ fc1w, const float* __restrict__ fc1b,
                const float* __restrict__ fc2w, const float* __restrict__ fc2b,
                float* __restrict__ out, int N)
{
    __shared__ float zs[96];
    __shared__ float z1[64];
    __shared__ float z2[32];
    __shared__ int seg[2];

    const int g = blockIdx.x;
    const int t = threadIdx.x;

    if (t < 2) {
        const int target = g + t;
        int lo = 0, hi = N;
        while (lo < hi) {
            const int mid = (lo + hi) >> 1;
            if (batch[mid] < target) lo = mid + 1; else hi = mid;
        }
        seg[t] = lo;
    }
    __syncthreads();

    float c = (float)(seg[1] - seg[0]);
    if (c < 1.f) c = 1.f;

    if (t < 32) zs[t] = gsum[g * 32 + t] / c;
    if (t >= 32 && t < 96) {
        const int j = t - 32;
        float u = 0.f;
#pragma unroll
        for (int r = 0; r < 5; ++r) u += ratios[r] * emb[(size_t)ids[r] * 64 + j];
        zs[32 + j] = u;
    }
    __syncthreads();

    if (t < 64) {
        float a = fc0b[t];
        for (int k = 0; k < 96; ++k) a += zs[k] * fc0w[k * 64 + t];
        z1[t] = a > 0.f ? a : 0.f;
    }
    __syncthreads();

    if (t < 32) {
        float a = fc1b[t];
        for (int k = 0; k < 64; ++k) a += z1[k] * fc1w[k * 32 + t];
        z2[t] = a > 0.f ? a : 0.f;
    }
    __syncthreads();

    if (t == 0) {
        float a = fc2b[0];
        for (int k = 0; k < 32; ++k) a += z2[k] * fc2w[k];
        out[g] = a;
    }
}

// ---------------------------------------------------------------------------
extern "C" void kernel_launch(void* const* d_in, const int* in_sizes, int n_in,
                              void* d_out, int out_size, void* d_ws, size_t ws_size,
                              hipStream_t stream)
{
    const float* x         = (const float*)d_in[0];
    const float* ea        = (const float*)d_in[1];
    const float* ratios    = (const float*)d_in[2];
    const int*   eidx      = (const int*)  d_in[3];
    const int*   batch     = (const int*)  d_in[4];
    const int*   ids       = (const int*)  d_in[5];
    const float* W1        = (const float*)d_in[6];
    const float* b1        = (const float*)d_in[7];
    const float* W2        = (const float*)d_in[8];
    const float* b2        = (const float*)d_in[9];
    const float* emb       = (const float*)d_in[10];
    const float* root      = (const float*)d_in[11];
    const float* conv_bias = (const float*)d_in[12];
    const float* fc0w      = (const float*)d_in[13];
    const float* fc0b      = (const float*)d_in[14];
    const float* fc1w      = (const float*)d_in[15];
    const float* fc1b      = (const float*)d_in[16];
    const float* fc2w      = (const float*)d_in[17];
    const float* fc2b      = (const float*)d_in[18];

    const int N = in_sizes[0] / NODE_DIM;   // 50000
    const int E = in_sizes[1] / 3;          // 1000000
    const int G = out_size;                 // 128

    float* s    = (float*)d_ws;                                               // [N,32]
    int*   cnt  = (int*)((char*)d_ws + (size_t)N * 32 * 4);                   // [N]
    float* gsum = (float*)((char*)d_ws + (size_t)N * 32 * 4 + (size_t)N * 4); // [G,32]
    (void)hipMemsetAsync(d_ws, 0, (size_t)N * 32 * 4 + (size_t)N * 4 + (size_t)G * 32 * 4, stream);

    edge_kernel<<<2048, 256, 0, stream>>>(x, ea, eidx, W1, b1, W2, b2, s, cnt, E);
    node_pool_kernel<<<(N + 7) / 8, 256, 0, stream>>>(s, cnt, x, root, conv_bias,
                                                      batch, gsum, N);
    mlp_kernel<<<G, 128, 0, stream>>>(gsum, batch, ratios, ids, emb,
                                      fc0w, fc0b, fc1w, fc1b, fc2w, fc2b,
                                      (float*)d_out, N);
}